// Round 13
// baseline (76.662 us; speedup 1.0000x reference)
//
#include <hip/hip_runtime.h>
#include <math.h>

// Problem constants: N=8192 nodes, IN=512, OUT=8192, HEADS=1.
#define NN   8192
#define INC  512
#define NDEG 128   // deg LDS-hist blocks/copies
#define NDV  8     // dinv finalize blocks (spin on deg flags)
#define NU   128   // u-partial blocks (64 rows each)
#define NV   128   // v blocks (4 rows of W each)
#define NADV 128   // adv LDS-hist blocks/copies
#define NXB  256   // x-pass blocks (32 rows each)
#define NK3  256   // k3 blocks
#define MAGIC 0x5EED9E37u

// ws float offsets — exact-write everywhere; CNT1/CNT2 zeroed by K1's c0
// block (proven mechanism); deg flags use MAGIC compare (no zeroing needed,
// replay-stale flags benign: DEGP is replay-invariant).
#define OFF_DEGP 0u          // [128][NN]
#define OFF_ADVP 1048576u    // [128][NN]
#define OFF_UP   2097152u    // [128][INC]
#define OFF_TP   2162688u    // [256][INC]
#define OFF_V    2293760u    // [512]
#define OFF_T    2294272u    // [512]
#define OFF_DINV 2294784u    // [NN]
#define OFF_XU   2302976u    // [NN]
#define OFF_ADVF 2311168u    // [NN]
#define OFF_S2P  2319360u    // [256]
#define OFF_SC   2319616u    // [0]=c0, [1]=scal1
#define OFF_CNT1 2319624u    // x-pass done-counter (zeroed by K1)
#define OFF_CNT2 2319632u    // k3 done-counter    (zeroed by K1)
#define OFF_FLG  2319648u    // [128] deg done-flags (MAGIC)

__device__ __forceinline__ unsigned bump(float* ws, unsigned off) {
    return __hip_atomic_fetch_add((unsigned*)(ws + off), 1u,
                                  __ATOMIC_ACQ_REL, __HIP_MEMORY_SCOPE_AGENT);
}

// ===========================================================================
// K1: [0,128): deg LDS-hist -> DEGP[b], release MAGIC flag
//     [128,136): dinv finalize — spin on 128 flags, sum copies, write DINV
//     [136,264): u partials (64 rows) | [264,392): v = W@a2 | 392: c0+zeros
__global__ __launch_bounds__(1024) void k1(
        const float* __restrict__ lin_w, const float* __restrict__ att,
        const float* __restrict__ lin_b, const float* __restrict__ weight,
        const int* __restrict__ row, int E, float* __restrict__ ws) {
    __shared__ float smem[8192];
    const int b = blockIdx.x, tid = threadIdx.x;

    if (b < NDEG) {                              // ---- deg histogram ----
        #pragma unroll
        for (int m = 0; m < 8; ++m) smem[tid + m * 1024] = 0.f;
        __syncthreads();
        const int per4 = (E >> 2) / NDEG;        // 512 int4 chunks per block
        const int4* r4 = (const int4*)row;
        for (int q = tid; q < per4; q += 1024) {
            int4 r = r4[b * per4 + q];
            atomicAdd(&smem[r.x], 1.f); atomicAdd(&smem[r.y], 1.f);
            atomicAdd(&smem[r.z], 1.f); atomicAdd(&smem[r.w], 1.f);
        }
        if (b == NDEG - 1)                       // generic tail
            for (int e = per4 * 4 * NDEG + tid; e < E; e += 1024)
                atomicAdd(&smem[row[e]], 1.f);
        __syncthreads();
        float4* dst = (float4*)(ws + OFF_DEGP) + b * 2048;
        dst[tid]        = ((float4*)smem)[tid];
        dst[tid + 1024] = ((float4*)smem)[tid + 1024];
        __syncthreads();                         // all stores before release
        if (tid == 0)
            __hip_atomic_store(((unsigned*)(ws + OFF_FLG)) + b, MAGIC,
                               __ATOMIC_RELEASE, __HIP_MEMORY_SCOPE_AGENT);
    } else if (b < NDEG + NDV) {                 // ---- dinv finalize ----
        if (tid == 0) {                          // spin until all deg done
            unsigned* flg = (unsigned*)(ws + OFF_FLG);
            for (int f = 0; f < NDEG; ++f)
                while (__hip_atomic_load(flg + f, __ATOMIC_ACQUIRE,
                                         __HIP_MEMORY_SCOPE_AGENT) != MAGIC) {}
        }
        __syncthreads();
        const int n = (b - NDEG) * 1024 + tid;   // 8 blocks x 1024 nodes
        const float* degp = ws + OFF_DEGP;
        float d = 0.f;
        #pragma unroll 8
        for (int cp = 0; cp < NDEG; ++cp) d += degp[cp * NN + n];
        ws[OFF_DINV + n] = 1.f / sqrtf(d);
    } else if (b < NDEG + NDV + NU) {            // ---- u partials ----
        float4* lds4 = (float4*)smem;
        const int r0 = (b - NDEG - NDV) * 64;
        const int c4 = tid & 127, rg = tid >> 7;
        float4 acc = {0.f, 0.f, 0.f, 0.f};
        #pragma unroll
        for (int it = 0; it < 8; ++it) {
            int r = r0 + rg * 8 + it;
            float w = att[r];
            float4 v = ((const float4*)(lin_w + (size_t)r * INC))[c4];
            acc.x += w * v.x; acc.y += w * v.y; acc.z += w * v.z; acc.w += w * v.w;
        }
        lds4[tid] = acc;
        __syncthreads();
        #pragma unroll
        for (int off = 4; off > 0; off >>= 1) {
            if (rg < off) {
                float4 o = lds4[(rg + off) * 128 + c4];
                float4 m = lds4[tid];
                m.x += o.x; m.y += o.y; m.z += o.z; m.w += o.w;
                lds4[tid] = m;
            }
            __syncthreads();
        }
        if (rg == 0)
            ((float4*)(ws + OFF_UP))[(b - NDEG - NDV) * 128 + c4] = lds4[c4];
    } else if (b < NDEG + NDV + NU + NV) {       // ---- v[c] = W[c,:].a2 ----
        const int r0 = (b - NDEG - NDV - NU) * 4;
        const int rg = tid >> 8, kl = tid & 255;
        const int c = r0 + rg;
        const float4* wrow = (const float4*)(weight + (size_t)c * NN);
        const float4* a2   = (const float4*)(att + NN);
        float acc = 0.f;
        #pragma unroll
        for (int q = 0; q < 8; ++q) {
            float4 wv = wrow[kl + q * 256];
            float4 av = a2[kl + q * 256];
            acc += wv.x * av.x + wv.y * av.y + wv.z * av.z + wv.w * av.w;
        }
        smem[rg * 256 + kl] = acc;
        __syncthreads();
        for (int off = 128; off > 0; off >>= 1) {
            if (kl < off) smem[rg * 256 + kl] += smem[rg * 256 + kl + off];
            __syncthreads();
        }
        if (kl == 0) ws[OFF_V + c] = smem[rg * 256];
    } else {                                     // ---- c0 + zero counters ----
        float v = 0.f;
        for (int i = tid; i < NN; i += 1024) v += lin_b[i] * att[i];
        smem[tid] = v;
        __syncthreads();
        for (int off = 512; off > 0; off >>= 1) {
            if (tid < off) smem[tid] += smem[tid + off];
            __syncthreads();
        }
        if (tid == 0) {
            ws[OFF_SC] = smem[0];
            *(unsigned*)(ws + OFF_CNT1) = 0u;    // kernel boundary orders these
            *(unsigned*)(ws + OFF_CNT2) = 0u;
        }
    }
}

// ===========================================================================
// K2: [0,256): x-pass 32 rows each — u rebuild (L2), dinv slice from DINV,
//              t partial -> TP[b], xu; last-done: t finalize + scal1 = t.v
//     [256,384): adv LDS-hist (dinv 32KB hot) -> exact ADVP
__global__ __launch_bounds__(1024) void k2(
        const float* __restrict__ x, const int* __restrict__ row,
        const int* __restrict__ col, int E, float* __restrict__ ws) {
    __shared__ float smem[16384];
    __shared__ int isLast;
    const int b = blockIdx.x, tid = threadIdx.x;

    if (b < NXB) {                               // ---- fused t + xu ----
        float4* lds4  = (float4*)smem;           // floats    0..4095 (t tree)
        float4* ured  = (float4*)(smem + 4096);  // floats 4096..8191
        float4* u4    = (float4*)(smem + 8192);  // floats 8192..8703
        float*  dinvl = smem + 8704;             // [32]
        float*  xured = smem + 8736;             // [64]
        const int r0 = b * 32;
        const int c4 = tid & 127, rg = tid >> 7, lane = tid & 63;

        {                                        // u = sum of 128 partials
            const float4* up = (const float4*)(ws + OFF_UP);
            float4 a = {0.f, 0.f, 0.f, 0.f};
            #pragma unroll
            for (int q = 0; q < 16; ++q) {
                float4 v = up[(rg * 16 + q) * 128 + c4];
                a.x += v.x; a.y += v.y; a.z += v.z; a.w += v.w;
            }
            ured[rg * 128 + c4] = a;
        }
        if (tid < 32) dinvl[tid] = ws[OFF_DINV + r0 + tid];
        __syncthreads();
        if (tid < 128) {
            float4 a = {0.f, 0.f, 0.f, 0.f};
            #pragma unroll
            for (int g = 0; g < 8; ++g) {
                float4 v = ured[g * 128 + tid];
                a.x += v.x; a.y += v.y; a.z += v.z; a.w += v.w;
            }
            u4[tid] = a;
        }
        __syncthreads();

        float4 accT = {0.f, 0.f, 0.f, 0.f};
        float xup[4];
        #pragma unroll
        for (int it = 0; it < 4; ++it) {
            int rl = rg + it * 8;
            float4 v = ((const float4*)(x + (size_t)(r0 + rl) * INC))[c4];
            float w = dinvl[rl];
            accT.x += w * v.x; accT.y += w * v.y; accT.z += w * v.z; accT.w += w * v.w;
            float4 uu = u4[c4];
            xup[it] = v.x * uu.x + v.y * uu.y + v.z * uu.z + v.w * uu.w;
        }
        #pragma unroll
        for (int it = 0; it < 4; ++it) {
            float a = xup[it];
            #pragma unroll
            for (int off = 32; off > 0; off >>= 1) a += __shfl_down(a, off);
            if (lane == 0) xured[rg * 8 + it * 2 + ((tid >> 6) & 1)] = a;
        }
        lds4[tid] = accT;
        __syncthreads();
        if (tid < 32) {                          // rl = rg + it*8
            int rl = tid, rg2 = rl & 7, it2 = rl >> 3;
            ws[OFF_XU + r0 + rl] =
                xured[rg2 * 8 + it2 * 2] + xured[rg2 * 8 + it2 * 2 + 1];
        }
        #pragma unroll
        for (int off = 4; off > 0; off >>= 1) {
            if (rg < off) {
                float4 o = lds4[(rg + off) * 128 + c4];
                float4 m = lds4[tid];
                m.x += o.x; m.y += o.y; m.z += o.z; m.w += o.w;
                lds4[tid] = m;
            }
            __syncthreads();
        }
        if (rg == 0) ((float4*)(ws + OFF_TP))[b * 128 + c4] = lds4[c4];
        __syncthreads();                         // all stores before election
        if (tid == 0) {
            unsigned old = bump(ws, OFF_CNT1);   // CNT1 zeroed by K1
            isLast = (old == NXB - 1);
        }
        __syncthreads();
        if (!isLast) return;
        // ---- t finalize + scal1 = t.v (hidden under adv-hist blocks) ----
        {
            const int colx = tid & 511, half = tid >> 9;
            const float* tp = ws + OFF_TP;
            float pv = 0.f;
            #pragma unroll 8
            for (int p = half * 128; p < half * 128 + 128; ++p)
                pv += tp[p * INC + colx];
            smem[tid] = pv;
        }
        __syncthreads();
        if (tid < 512) {
            float tv = smem[tid] + smem[tid + 512];
            ws[OFF_T + tid] = tv;
            smem[tid] = tv * ws[OFF_V + tid];
        }
        __syncthreads();
        for (int off = 256; off > 0; off >>= 1) {
            if (tid < off) smem[tid] += smem[tid + off];
            __syncthreads();
        }
        if (tid == 0) ws[OFF_SC + 1] = smem[0];
    } else {                                     // ---- adv histogram ----
        const int bb = b - NXB;                  // 0..127
        float* dl = smem;                        // dinv [8192]
        float* al = smem + 8192;                 // adv  [8192]
        const float4* dv = (const float4*)(ws + OFF_DINV);
        ((float4*)dl)[tid]        = dv[tid];
        ((float4*)dl)[tid + 1024] = dv[tid + 1024];
        #pragma unroll
        for (int m = 0; m < 8; ++m) al[tid + m * 1024] = 0.f;
        __syncthreads();
        const int per4 = (E >> 2) / NADV;        // 512
        const int4* r4  = (const int4*)row;
        const int4* c4p = (const int4*)col;
        for (int q = tid; q < per4; q += 1024) {
            int4 r = r4[bb * per4 + q];
            int4 c = c4p[bb * per4 + q];
            atomicAdd(&al[r.x], dl[c.x]); atomicAdd(&al[r.y], dl[c.y]);
            atomicAdd(&al[r.z], dl[c.z]); atomicAdd(&al[r.w], dl[c.w]);
        }
        if (bb == NADV - 1)
            for (int e = per4 * 4 * NADV + tid; e < E; e += 1024)
                atomicAdd(&al[row[e]], dl[col[e]]);
        __syncthreads();
        float4* dst = (float4*)(ws + OFF_ADVP) + bb * 2048;
        dst[tid]        = ((float4*)al)[tid];
        dst[tid + 1024] = ((float4*)al)[tid + 1024];
    }
}

// ===========================================================================
// K3 (256 blocks, 32-wide k/i windows): s[k] full-c dot over W; adv = sum of
// 128 ADVP copies; alpha + s2 partial; last-done block: scal2 + out.
__global__ __launch_bounds__(1024) void k3(
        const float* __restrict__ weight, const float* __restrict__ bias,
        float* __restrict__ ws, float* __restrict__ out) {
    __shared__ float smem[4096];
    __shared__ int isLast;
    float* t_lds = smem;            // [512]
    float* gmat  = smem + 512;      // [32*33]
    float* amat  = smem + 1568;     // [32*33]
    const int b = blockIdx.x, tid = threadIdx.x;

    if (tid < 512) t_lds[tid] = ws[OFF_T + tid];
    __syncthreads();

    const int g = tid >> 5, kl = tid & 31;
    const int k = b * 32 + kl;
    float acc = 0.f;
    #pragma unroll
    for (int q = 0; q < 16; ++q) {
        int c = g + (q << 5);
        acc += t_lds[c] * weight[(size_t)c * NN + k];
    }
    gmat[g * 33 + kl] = acc;
    {   // adv copies: group g sums copies 4g..4g+3 for node kl
        const float* ap = ws + OFF_ADVP;
        int i = b * 32 + kl;
        float a = 0.f;
        #pragma unroll
        for (int j = 0; j < 4; ++j) a += ap[(size_t)(4 * g + j) * NN + i];
        amat[g * 33 + kl] = a;
    }
    __syncthreads();
    if (tid < 32) {
        float sv = 0.f, av = 0.f;
        #pragma unroll
        for (int j = 0; j < 32; ++j) {
            sv += gmat[j * 33 + tid];
            av += amat[j * 33 + tid];
        }
        int i = b * 32 + tid;
        float a  = ws[OFF_XU + i] + ws[OFF_SC] + av * ws[OFF_SC + 1];
        float lr = a > 0.f ? a : 0.2f * a;
        float part = sv * lr;
        ws[OFF_ADVF + i] = av;
        #pragma unroll
        for (int off = 16; off > 0; off >>= 1) part += __shfl_down(part, off);
        if (tid == 0) ws[OFF_S2P + b] = part;
    }
    __syncthreads();
    if (tid == 0) {
        unsigned old = bump(ws, OFF_CNT2);   // CNT2 zeroed by K1 this launch
        isLast = (old == NK3 - 1);
    }
    __syncthreads();
    if (!isLast) return;

    // ---- last block: scal2 (fixed-order tree, deterministic) + out ----
    smem[tid] = (tid < 256) ? ws[OFF_S2P + tid] : 0.f;
    __syncthreads();
    for (int off = 512; off > 0; off >>= 1) {
        if (tid < off) smem[tid] += smem[tid + off];
        __syncthreads();
    }
    const float s2 = smem[0];
    #pragma unroll
    for (int m = 0; m < 8; ++m) {
        int i = tid + m * 1024;
        float v = ws[OFF_ADVF + i] * s2 + bias[i];
        out[i] = v > 0.f ? v : 0.f;
    }
}

// ===========================================================================
extern "C" void kernel_launch(void* const* d_in, const int* in_sizes, int n_in,
                              void* d_out, int out_size, void* d_ws, size_t ws_size,
                              hipStream_t stream) {
    const float* x      = (const float*)d_in[0];   // [8192, 512]
    const int*   eidx   = (const int*)d_in[1];     // [2, E]
    const float* weight = (const float*)d_in[2];   // [512, 8192]
    const float* bias   = (const float*)d_in[3];   // [8192]
    const float* att    = (const float*)d_in[4];   // [16384]
    const float* lin_w  = (const float*)d_in[5];   // [8192, 512]
    const float* lin_b  = (const float*)d_in[6];   // [8192]

    const int E = in_sizes[1] / 2;
    const int* row = eidx;
    const int* col = eidx + E;
    float* ws  = (float*)d_ws;
    float* out = (float*)d_out;

    k1<<<NDEG + NDV + NU + NV + 1, 1024, 0, stream>>>(lin_w, att, lin_b, weight, row, E, ws);
    k2<<<NXB + NADV, 1024, 0, stream>>>(x, row, col, E, ws);
    k3<<<NK3,        1024, 0, stream>>>(weight, bias, ws, out);
}

// Round 14
// 45.522 us; speedup vs baseline: 1.6841x; 1.6841x over previous
//
#include <hip/hip_runtime.h>
#include <math.h>

// Problem constants: N=8192 nodes, IN=512, OUT=8192, HEADS=1.
// R14 = exact revert to R12 (best measured: 46.1 us). R13's in-kernel
// spin handoff regressed (kernel-boundary sync is the cheapest cross-XCD
// barrier: ~5-6 us/gap vs ~30 us spin vs ~25-30 us grid.sync).
#define NN   8192
#define INC  512
#define NDEG 128   // deg LDS-hist blocks/copies
#define NU   128   // u-partial blocks (64 rows each)
#define NV   128   // v blocks (4 rows of W each)
#define NADV 128   // adv LDS-hist blocks/copies
#define NXB  256   // x-pass blocks (32 rows each)
#define NK4  256   // k4 blocks

// ws float offsets — every slot exact-written; CNT2 zeroed by K1 (proven
// mechanism: zero in a prior kernel, check old == N-1).
#define OFF_DEGP 0u          // [128][NN]
#define OFF_ADVP 1048576u    // [128][NN]
#define OFF_UP   2097152u    // [128][INC]
#define OFF_TP   2162688u    // [256][INC]
#define OFF_V    2293760u    // [512]
#define OFF_T    2294272u    // [512]
#define OFF_DINV 2294784u    // [NN]
#define OFF_XU   2302976u    // [NN]
#define OFF_ADVF 2311168u    // [NN]
#define OFF_S2P  2319360u    // [256]
#define OFF_SC   2319616u    // [0]=c0, [1]=scal1
#define OFF_CNT2 2319624u    // k4 done-counter (zeroed by K1)

__device__ __forceinline__ unsigned bump(float* ws, unsigned off) {
    return __hip_atomic_fetch_add((unsigned*)(ws + off), 1u,
                                  __ATOMIC_ACQ_REL, __HIP_MEMORY_SCOPE_AGENT);
}

// ===========================================================================
// K1: b<128: deg LDS-hist -> DEGP[b] | 128..255: u partials (64 rows each)
//     256..383: v = W@a2 (4 rows each) | b=384: c0 + zero CNT2
__global__ __launch_bounds__(1024) void k1(
        const float* __restrict__ lin_w, const float* __restrict__ att,
        const float* __restrict__ lin_b, const float* __restrict__ weight,
        const int* __restrict__ row, int E, float* __restrict__ ws) {
    __shared__ float smem[8192];
    const int b = blockIdx.x, tid = threadIdx.x;

    if (b < NDEG) {                              // ---- deg histogram ----
        #pragma unroll
        for (int m = 0; m < 8; ++m) smem[tid + m * 1024] = 0.f;
        __syncthreads();
        const int per4 = (E >> 2) / NDEG;        // 512 int4 chunks per block
        const int4* r4 = (const int4*)row;
        for (int q = tid; q < per4; q += 1024) {
            int4 r = r4[b * per4 + q];
            atomicAdd(&smem[r.x], 1.f); atomicAdd(&smem[r.y], 1.f);
            atomicAdd(&smem[r.z], 1.f); atomicAdd(&smem[r.w], 1.f);
        }
        if (b == NDEG - 1)                       // generic tail (empty here)
            for (int e = per4 * 4 * NDEG + tid; e < E; e += 1024)
                atomicAdd(&smem[row[e]], 1.f);
        __syncthreads();
        float4* dst = (float4*)(ws + OFF_DEGP) + b * 2048;
        dst[tid]        = ((float4*)smem)[tid];
        dst[tid + 1024] = ((float4*)smem)[tid + 1024];
    } else if (b < NDEG + NU) {                  // ---- u partials ----
        float4* lds4 = (float4*)smem;
        const int r0 = (b - NDEG) * 64;
        const int c4 = tid & 127, rg = tid >> 7;
        float4 acc = {0.f, 0.f, 0.f, 0.f};
        #pragma unroll
        for (int it = 0; it < 8; ++it) {
            int r = r0 + rg * 8 + it;
            float w = att[r];
            float4 v = ((const float4*)(lin_w + (size_t)r * INC))[c4];
            acc.x += w * v.x; acc.y += w * v.y; acc.z += w * v.z; acc.w += w * v.w;
        }
        lds4[tid] = acc;
        __syncthreads();
        #pragma unroll
        for (int off = 4; off > 0; off >>= 1) {
            if (rg < off) {
                float4 o = lds4[(rg + off) * 128 + c4];
                float4 m = lds4[tid];
                m.x += o.x; m.y += o.y; m.z += o.z; m.w += o.w;
                lds4[tid] = m;
            }
            __syncthreads();
        }
        if (rg == 0) ((float4*)(ws + OFF_UP))[(b - NDEG) * 128 + c4] = lds4[c4];
    } else if (b < NDEG + NU + NV) {             // ---- v[c] = W[c,:].a2 ----
        const int r0 = (b - NDEG - NU) * 4;
        const int rg = tid >> 8, kl = tid & 255;
        const int c = r0 + rg;
        const float4* wrow = (const float4*)(weight + (size_t)c * NN);
        const float4* a2   = (const float4*)(att + NN);
        float acc = 0.f;
        #pragma unroll
        for (int q = 0; q < 8; ++q) {
            float4 wv = wrow[kl + q * 256];
            float4 av = a2[kl + q * 256];
            acc += wv.x * av.x + wv.y * av.y + wv.z * av.z + wv.w * av.w;
        }
        smem[rg * 256 + kl] = acc;
        __syncthreads();
        for (int off = 128; off > 0; off >>= 1) {
            if (kl < off) smem[rg * 256 + kl] += smem[rg * 256 + kl + off];
            __syncthreads();
        }
        if (kl == 0) ws[OFF_V + c] = smem[rg * 256];
    } else {                                     // ---- c0 + zero CNT2 ----
        float v = 0.f;
        for (int i = tid; i < NN; i += 1024) v += lin_b[i] * att[i];
        smem[tid] = v;
        __syncthreads();
        for (int off = 512; off > 0; off >>= 1) {
            if (tid < off) smem[tid] += smem[tid + off];
            __syncthreads();
        }
        if (tid == 0) {
            ws[OFF_SC] = smem[0];
            *(unsigned*)(ws + OFF_CNT2) = 0u;    // kernel boundary orders this
        }
    }
}

// ===========================================================================
// K2 (256 blocks, 32 rows each): rebuild u from 128 UP partials (L2-hot);
// dinv for own 32 rows from DEGP (also exact-stored to OFF_DINV for K3);
// t partial (exact -> TP[b]) + xu. No done-counter, no tail.
__global__ __launch_bounds__(1024) void k2(
        const float* __restrict__ x, float* __restrict__ ws) {
    __shared__ float smem[8800];
    float4* lds4  = (float4*)smem;           // floats    0..4095 (t tree)
    float4* ured  = (float4*)(smem + 4096);  // floats 4096..8191
    float4* u4    = (float4*)(smem + 8192);  // floats 8192..8703
    float*  dinvl = smem + 8704;             // [32]
    float*  xured = smem + 8736;             // [64]
    const int b = blockIdx.x, tid = threadIdx.x;
    const int r0 = b * 32;
    const int c4 = tid & 127, rg = tid >> 7, lane = tid & 63;

    {                                        // u = sum of 128 partials
        const float4* up = (const float4*)(ws + OFF_UP);
        float4 a = {0.f, 0.f, 0.f, 0.f};
        #pragma unroll
        for (int q = 0; q < 16; ++q) {
            float4 v = up[(rg * 16 + q) * 128 + c4];
            a.x += v.x; a.y += v.y; a.z += v.z; a.w += v.w;
        }
        ured[rg * 128 + c4] = a;
    }
    if (tid >= 128 && tid < 160) {           // dinv for this block's 32 rows
        int rl = tid - 128;
        const float* degp = ws + OFF_DEGP;
        float d = 0.f;
        #pragma unroll 8
        for (int cp = 0; cp < NDEG; ++cp) d += degp[cp * NN + r0 + rl];
        float dvv = 1.f / sqrtf(d);
        dinvl[rl] = dvv;
        ws[OFF_DINV + r0 + rl] = dvv;        // exact-write slice for K3
    }
    __syncthreads();
    if (tid < 128) {
        float4 a = {0.f, 0.f, 0.f, 0.f};
        #pragma unroll
        for (int g = 0; g < 8; ++g) {
            float4 v = ured[g * 128 + tid];
            a.x += v.x; a.y += v.y; a.z += v.z; a.w += v.w;
        }
        u4[tid] = a;
    }
    __syncthreads();

    float4 accT = {0.f, 0.f, 0.f, 0.f};
    float xup[4];
    #pragma unroll
    for (int it = 0; it < 4; ++it) {
        int rl = rg + it * 8;
        float4 v = ((const float4*)(x + (size_t)(r0 + rl) * INC))[c4];
        float w = dinvl[rl];
        accT.x += w * v.x; accT.y += w * v.y; accT.z += w * v.z; accT.w += w * v.w;
        float4 uu = u4[c4];
        xup[it] = v.x * uu.x + v.y * uu.y + v.z * uu.z + v.w * uu.w;
    }
    #pragma unroll
    for (int it = 0; it < 4; ++it) {
        float a = xup[it];
        #pragma unroll
        for (int off = 32; off > 0; off >>= 1) a += __shfl_down(a, off);
        if (lane == 0) xured[rg * 8 + it * 2 + ((tid >> 6) & 1)] = a;
    }
    lds4[tid] = accT;
    __syncthreads();
    if (tid < 32) {                          // rl = rg + it*8
        int rl = tid, rg2 = rl & 7, it2 = rl >> 3;
        ws[OFF_XU + r0 + rl] =
            xured[rg2 * 8 + it2 * 2] + xured[rg2 * 8 + it2 * 2 + 1];
    }
    #pragma unroll
    for (int off = 4; off > 0; off >>= 1) {
        if (rg < off) {
            float4 o = lds4[(rg + off) * 128 + c4];
            float4 m = lds4[tid];
            m.x += o.x; m.y += o.y; m.z += o.z; m.w += o.w;
            lds4[tid] = m;
        }
        __syncthreads();
    }
    if (rg == 0) ((float4*)(ws + OFF_TP))[b * 128 + c4] = lds4[c4];
}

// ===========================================================================
// K3 (129 blocks): b<128: adv LDS-hist (dinv 32KB hot) -> exact ADVP[b].
//                  b==128: t finalize (sum 256 TP partials) + scal1 = t.v.
__global__ __launch_bounds__(1024) void k3(
        const int* __restrict__ row, const int* __restrict__ col, int E,
        float* __restrict__ ws) {
    __shared__ float smem[16384];
    const int b = blockIdx.x, tid = threadIdx.x;

    if (b < NADV) {                          // ---- adv histogram ----
        float* dl = smem;                    // dinv [8192]
        float* al = smem + 8192;             // adv  [8192]
        const float4* dv = (const float4*)(ws + OFF_DINV);
        ((float4*)dl)[tid]        = dv[tid];
        ((float4*)dl)[tid + 1024] = dv[tid + 1024];
        #pragma unroll
        for (int m = 0; m < 8; ++m) al[tid + m * 1024] = 0.f;
        __syncthreads();
        const int per4 = (E >> 2) / NADV;    // 512
        const int4* r4  = (const int4*)row;
        const int4* c4p = (const int4*)col;
        for (int q = tid; q < per4; q += 1024) {
            int4 r = r4[b * per4 + q];
            int4 c = c4p[b * per4 + q];
            atomicAdd(&al[r.x], dl[c.x]); atomicAdd(&al[r.y], dl[c.y]);
            atomicAdd(&al[r.z], dl[c.z]); atomicAdd(&al[r.w], dl[c.w]);
        }
        if (b == NADV - 1)
            for (int e = per4 * 4 * NADV + tid; e < E; e += 1024)
                atomicAdd(&al[row[e]], dl[col[e]]);
        __syncthreads();
        float4* dst = (float4*)(ws + OFF_ADVP) + b * 2048;
        dst[tid]        = ((float4*)al)[tid];
        dst[tid + 1024] = ((float4*)al)[tid + 1024];
    } else {                                 // ---- t + scal1 finalize ----
        const int colx = tid & 511, half = tid >> 9;
        const float* tp = ws + OFF_TP;
        float pv = 0.f;
        #pragma unroll 8
        for (int p = half * 128; p < half * 128 + 128; ++p)
            pv += tp[p * INC + colx];
        smem[tid] = pv;
        __syncthreads();
        if (tid < 512) {
            float tv = smem[tid] + smem[tid + 512];
            ws[OFF_T + tid] = tv;
            smem[tid] = tv * ws[OFF_V + tid];
        }
        __syncthreads();
        for (int off = 256; off > 0; off >>= 1) {
            if (tid < off) smem[tid] += smem[tid + off];
            __syncthreads();
        }
        if (tid == 0) ws[OFF_SC + 1] = smem[0];
    }
}

// ===========================================================================
// K4 (256 blocks, 32-wide k/i windows): s[k] full-c dot over W; adv = sum of
// 128 ADVP copies; alpha + s2 partial; last-done block: scal2 + out.
__global__ __launch_bounds__(1024) void k4(
        const float* __restrict__ weight, const float* __restrict__ bias,
        float* __restrict__ ws, float* __restrict__ out) {
    __shared__ float smem[4096];
    __shared__ int isLast;
    float* t_lds = smem;            // [512]
    float* gmat  = smem + 512;      // [32*33]
    float* amat  = smem + 1568;     // [32*33]
    const int b = blockIdx.x, tid = threadIdx.x;

    if (tid < 512) t_lds[tid] = ws[OFF_T + tid];
    __syncthreads();

    const int g = tid >> 5, kl = tid & 31;
    const int k = b * 32 + kl;
    float acc = 0.f;
    #pragma unroll
    for (int q = 0; q < 16; ++q) {
        int c = g + (q << 5);
        acc += t_lds[c] * weight[(size_t)c * NN + k];
    }
    gmat[g * 33 + kl] = acc;
    {   // adv copies: group g sums copies 4g..4g+3 for node kl
        const float* ap = ws + OFF_ADVP;
        int i = b * 32 + kl;
        float a = 0.f;
        #pragma unroll
        for (int j = 0; j < 4; ++j) a += ap[(size_t)(4 * g + j) * NN + i];
        amat[g * 33 + kl] = a;
    }
    __syncthreads();
    if (tid < 32) {
        float sv = 0.f, av = 0.f;
        #pragma unroll
        for (int j = 0; j < 32; ++j) {
            sv += gmat[j * 33 + tid];
            av += amat[j * 33 + tid];
        }
        int i = b * 32 + tid;
        float a  = ws[OFF_XU + i] + ws[OFF_SC] + av * ws[OFF_SC + 1];
        float lr = a > 0.f ? a : 0.2f * a;
        float part = sv * lr;
        ws[OFF_ADVF + i] = av;
        #pragma unroll
        for (int off = 16; off > 0; off >>= 1) part += __shfl_down(part, off);
        if (tid == 0) ws[OFF_S2P + b] = part;
    }
    __syncthreads();
    if (tid == 0) {
        unsigned old = bump(ws, OFF_CNT2);   // CNT2 zeroed by K1 this launch
        isLast = (old == NK4 - 1);
    }
    __syncthreads();
    if (!isLast) return;

    // ---- last block: scal2 (fixed-order tree, deterministic) + out ----
    smem[tid] = (tid < 256) ? ws[OFF_S2P + tid] : 0.f;
    __syncthreads();
    for (int off = 512; off > 0; off >>= 1) {
        if (tid < off) smem[tid] += smem[tid + off];
        __syncthreads();
    }
    const float s2 = smem[0];
    #pragma unroll
    for (int m = 0; m < 8; ++m) {
        int i = tid + m * 1024;
        float v = ws[OFF_ADVF + i] * s2 + bias[i];
        out[i] = v > 0.f ? v : 0.f;
    }
}

// ===========================================================================
extern "C" void kernel_launch(void* const* d_in, const int* in_sizes, int n_in,
                              void* d_out, int out_size, void* d_ws, size_t ws_size,
                              hipStream_t stream) {
    const float* x      = (const float*)d_in[0];   // [8192, 512]
    const int*   eidx   = (const int*)d_in[1];     // [2, E]
    const float* weight = (const float*)d_in[2];   // [512, 8192]
    const float* bias   = (const float*)d_in[3];   // [8192]
    const float* att    = (const float*)d_in[4];   // [16384]
    const float* lin_w  = (const float*)d_in[5];   // [8192, 512]
    const float* lin_b  = (const float*)d_in[6];   // [8192]

    const int E = in_sizes[1] / 2;
    const int* row = eidx;
    const int* col = eidx + E;
    float* ws  = (float*)d_ws;
    float* out = (float*)d_out;

    k1<<<NDEG + NU + NV + 1, 1024, 0, stream>>>(lin_w, att, lin_b, weight, row, E, ws);
    k2<<<NXB,      1024, 0, stream>>>(x, ws);
    k3<<<NADV + 1, 1024, 0, stream>>>(row, col, E, ws);
    k4<<<NK4,      1024, 0, stream>>>(weight, bias, ws, out);
}

// Round 15
// 44.254 us; speedup vs baseline: 1.7323x; 1.0287x over previous
//
#include <hip/hip_runtime.h>
#include <math.h>

// Problem constants: N=8192 nodes, IN=512, OUT=8192, HEADS=1.
// R15 = R14 minus the v=W@a2 branch: scal1 = s.a2 is now computed inside
// K4's last-done tail (s-blocks emit s + s.a2 partials + ADVF first).
// Removes the second 16 MB read of `weight` and shrinks K1 by 128 blocks.
#define NN   8192
#define INC  512
#define NDEG 128   // deg LDS-hist blocks/copies
#define NU   128   // u-partial blocks (64 rows each)
#define NADV 128   // adv LDS-hist blocks/copies
#define NXB  256   // x-pass blocks (32 rows each)
#define NK4  256   // k4 blocks

// ws float offsets — every slot exact-written; CNT2 zeroed by K1 (proven
// mechanism: zero in a prior kernel, check old == N-1).
#define OFF_DEGP 0u          // [128][NN]
#define OFF_ADVP 1048576u    // [128][NN]
#define OFF_UP   2097152u    // [128][INC]
#define OFF_TP   2162688u    // [256][INC]
#define OFF_T    2294272u    // [512]
#define OFF_DINV 2294784u    // [NN]
#define OFF_XU   2302976u    // [NN]
#define OFF_ADVF 2311168u    // [NN]
#define OFF_S1P  2319360u    // [256] s.a2 block partials
#define OFF_SC   2319616u    // [0]=c0
#define OFF_CNT2 2319624u    // k4 done-counter (zeroed by K1)
#define OFF_S    2319872u    // [NN] s vector

__device__ __forceinline__ unsigned bump(float* ws, unsigned off) {
    return __hip_atomic_fetch_add((unsigned*)(ws + off), 1u,
                                  __ATOMIC_ACQ_REL, __HIP_MEMORY_SCOPE_AGENT);
}

// ===========================================================================
// K1: b<128: deg LDS-hist -> DEGP[b] | 128..255: u partials (64 rows each)
//     b=256: c0 + zero CNT2
__global__ __launch_bounds__(1024) void k1(
        const float* __restrict__ lin_w, const float* __restrict__ att,
        const float* __restrict__ lin_b, const int* __restrict__ row,
        int E, float* __restrict__ ws) {
    __shared__ float smem[8192];
    const int b = blockIdx.x, tid = threadIdx.x;

    if (b < NDEG) {                              // ---- deg histogram ----
        #pragma unroll
        for (int m = 0; m < 8; ++m) smem[tid + m * 1024] = 0.f;
        __syncthreads();
        const int per4 = (E >> 2) / NDEG;        // 512 int4 chunks per block
        const int4* r4 = (const int4*)row;
        for (int q = tid; q < per4; q += 1024) {
            int4 r = r4[b * per4 + q];
            atomicAdd(&smem[r.x], 1.f); atomicAdd(&smem[r.y], 1.f);
            atomicAdd(&smem[r.z], 1.f); atomicAdd(&smem[r.w], 1.f);
        }
        if (b == NDEG - 1)                       // generic tail (empty here)
            for (int e = per4 * 4 * NDEG + tid; e < E; e += 1024)
                atomicAdd(&smem[row[e]], 1.f);
        __syncthreads();
        float4* dst = (float4*)(ws + OFF_DEGP) + b * 2048;
        dst[tid]        = ((float4*)smem)[tid];
        dst[tid + 1024] = ((float4*)smem)[tid + 1024];
    } else if (b < NDEG + NU) {                  // ---- u partials ----
        float4* lds4 = (float4*)smem;
        const int r0 = (b - NDEG) * 64;
        const int c4 = tid & 127, rg = tid >> 7;
        float4 acc = {0.f, 0.f, 0.f, 0.f};
        #pragma unroll
        for (int it = 0; it < 8; ++it) {
            int r = r0 + rg * 8 + it;
            float w = att[r];
            float4 v = ((const float4*)(lin_w + (size_t)r * INC))[c4];
            acc.x += w * v.x; acc.y += w * v.y; acc.z += w * v.z; acc.w += w * v.w;
        }
        lds4[tid] = acc;
        __syncthreads();
        #pragma unroll
        for (int off = 4; off > 0; off >>= 1) {
            if (rg < off) {
                float4 o = lds4[(rg + off) * 128 + c4];
                float4 m = lds4[tid];
                m.x += o.x; m.y += o.y; m.z += o.z; m.w += o.w;
                lds4[tid] = m;
            }
            __syncthreads();
        }
        if (rg == 0) ((float4*)(ws + OFF_UP))[(b - NDEG) * 128 + c4] = lds4[c4];
    } else {                                     // ---- c0 + zero CNT2 ----
        float v = 0.f;
        for (int i = tid; i < NN; i += 1024) v += lin_b[i] * att[i];
        smem[tid] = v;
        __syncthreads();
        for (int off = 512; off > 0; off >>= 1) {
            if (tid < off) smem[tid] += smem[tid + off];
            __syncthreads();
        }
        if (tid == 0) {
            ws[OFF_SC] = smem[0];
            *(unsigned*)(ws + OFF_CNT2) = 0u;    // kernel boundary orders this
        }
    }
}

// ===========================================================================
// K2 (256 blocks, 32 rows each): rebuild u from 128 UP partials (L2-hot);
// dinv for own 32 rows from DEGP (also exact-stored to OFF_DINV for K3);
// t partial (exact -> TP[b]) + xu. No done-counter, no tail.
__global__ __launch_bounds__(1024) void k2(
        const float* __restrict__ x, float* __restrict__ ws) {
    __shared__ float smem[8800];
    float4* lds4  = (float4*)smem;           // floats    0..4095 (t tree)
    float4* ured  = (float4*)(smem + 4096);  // floats 4096..8191
    float4* u4    = (float4*)(smem + 8192);  // floats 8192..8703
    float*  dinvl = smem + 8704;             // [32]
    float*  xured = smem + 8736;             // [64]
    const int b = blockIdx.x, tid = threadIdx.x;
    const int r0 = b * 32;
    const int c4 = tid & 127, rg = tid >> 7, lane = tid & 63;

    {                                        // u = sum of 128 partials
        const float4* up = (const float4*)(ws + OFF_UP);
        float4 a = {0.f, 0.f, 0.f, 0.f};
        #pragma unroll
        for (int q = 0; q < 16; ++q) {
            float4 v = up[(rg * 16 + q) * 128 + c4];
            a.x += v.x; a.y += v.y; a.z += v.z; a.w += v.w;
        }
        ured[rg * 128 + c4] = a;
    }
    if (tid >= 128 && tid < 160) {           // dinv for this block's 32 rows
        int rl = tid - 128;
        const float* degp = ws + OFF_DEGP;
        float d = 0.f;
        #pragma unroll 8
        for (int cp = 0; cp < NDEG; ++cp) d += degp[cp * NN + r0 + rl];
        float dvv = 1.f / sqrtf(d);
        dinvl[rl] = dvv;
        ws[OFF_DINV + r0 + rl] = dvv;        // exact-write slice for K3
    }
    __syncthreads();
    if (tid < 128) {
        float4 a = {0.f, 0.f, 0.f, 0.f};
        #pragma unroll
        for (int g = 0; g < 8; ++g) {
            float4 v = ured[g * 128 + tid];
            a.x += v.x; a.y += v.y; a.z += v.z; a.w += v.w;
        }
        u4[tid] = a;
    }
    __syncthreads();

    float4 accT = {0.f, 0.f, 0.f, 0.f};
    float xup[4];
    #pragma unroll
    for (int it = 0; it < 4; ++it) {
        int rl = rg + it * 8;
        float4 v = ((const float4*)(x + (size_t)(r0 + rl) * INC))[c4];
        float w = dinvl[rl];
        accT.x += w * v.x; accT.y += w * v.y; accT.z += w * v.z; accT.w += w * v.w;
        float4 uu = u4[c4];
        xup[it] = v.x * uu.x + v.y * uu.y + v.z * uu.z + v.w * uu.w;
    }
    #pragma unroll
    for (int it = 0; it < 4; ++it) {
        float a = xup[it];
        #pragma unroll
        for (int off = 32; off > 0; off >>= 1) a += __shfl_down(a, off);
        if (lane == 0) xured[rg * 8 + it * 2 + ((tid >> 6) & 1)] = a;
    }
    lds4[tid] = accT;
    __syncthreads();
    if (tid < 32) {                          // rl = rg + it*8
        int rl = tid, rg2 = rl & 7, it2 = rl >> 3;
        ws[OFF_XU + r0 + rl] =
            xured[rg2 * 8 + it2 * 2] + xured[rg2 * 8 + it2 * 2 + 1];
    }
    #pragma unroll
    for (int off = 4; off > 0; off >>= 1) {
        if (rg < off) {
            float4 o = lds4[(rg + off) * 128 + c4];
            float4 m = lds4[tid];
            m.x += o.x; m.y += o.y; m.z += o.z; m.w += o.w;
            lds4[tid] = m;
        }
        __syncthreads();
    }
    if (rg == 0) ((float4*)(ws + OFF_TP))[b * 128 + c4] = lds4[c4];
}

// ===========================================================================
// K3 (129 blocks): b<128: adv LDS-hist (dinv 32KB hot) -> exact ADVP[b].
//                  b==128: t finalize (sum 256 TP partials) -> OFF_T.
__global__ __launch_bounds__(1024) void k3(
        const int* __restrict__ row, const int* __restrict__ col, int E,
        float* __restrict__ ws) {
    __shared__ float smem[16384];
    const int b = blockIdx.x, tid = threadIdx.x;

    if (b < NADV) {                          // ---- adv histogram ----
        float* dl = smem;                    // dinv [8192]
        float* al = smem + 8192;             // adv  [8192]
        const float4* dv = (const float4*)(ws + OFF_DINV);
        ((float4*)dl)[tid]        = dv[tid];
        ((float4*)dl)[tid + 1024] = dv[tid + 1024];
        #pragma unroll
        for (int m = 0; m < 8; ++m) al[tid + m * 1024] = 0.f;
        __syncthreads();
        const int per4 = (E >> 2) / NADV;    // 512
        const int4* r4  = (const int4*)row;
        const int4* c4p = (const int4*)col;
        for (int q = tid; q < per4; q += 1024) {
            int4 r = r4[b * per4 + q];
            int4 c = c4p[b * per4 + q];
            atomicAdd(&al[r.x], dl[c.x]); atomicAdd(&al[r.y], dl[c.y]);
            atomicAdd(&al[r.z], dl[c.z]); atomicAdd(&al[r.w], dl[c.w]);
        }
        if (b == NADV - 1)
            for (int e = per4 * 4 * NADV + tid; e < E; e += 1024)
                atomicAdd(&al[row[e]], dl[col[e]]);
        __syncthreads();
        float4* dst = (float4*)(ws + OFF_ADVP) + b * 2048;
        dst[tid]        = ((float4*)al)[tid];
        dst[tid + 1024] = ((float4*)al)[tid + 1024];
    } else {                                 // ---- t finalize ----
        const int colx = tid & 511, half = tid >> 9;
        const float* tp = ws + OFF_TP;
        float pv = 0.f;
        #pragma unroll 8
        for (int p = half * 128; p < half * 128 + 128; ++p)
            pv += tp[p * INC + colx];
        smem[tid] = pv;
        __syncthreads();
        if (tid < 512) ws[OFF_T + tid] = smem[tid] + smem[tid + 512];
    }
}

// ===========================================================================
// K4 (256 blocks, 32-wide k/i windows): s[k] full-c dot over W -> OFF_S;
// s.a2 block partial -> S1P; adv = sum of 128 ADVP copies -> ADVF.
// Last-done block: scal1 = sum(S1P); alpha; s2 = dot(s, alpha); out.
__global__ __launch_bounds__(1024) void k4(
        const float* __restrict__ weight, const float* __restrict__ att,
        const float* __restrict__ bias, float* __restrict__ ws,
        float* __restrict__ out) {
    __shared__ float smem[4096];
    __shared__ int isLast;
    float* t_lds = smem;            // [512]
    float* gmat  = smem + 512;      // [32*33]
    float* amat  = smem + 1568;     // [32*33]
    const int b = blockIdx.x, tid = threadIdx.x;

    if (tid < 512) t_lds[tid] = ws[OFF_T + tid];
    __syncthreads();

    const int g = tid >> 5, kl = tid & 31;
    const int k = b * 32 + kl;
    float acc = 0.f;
    #pragma unroll
    for (int q = 0; q < 16; ++q) {
        int c = g + (q << 5);
        acc += t_lds[c] * weight[(size_t)c * NN + k];
    }
    gmat[g * 33 + kl] = acc;
    {   // adv copies: group g sums copies 4g..4g+3 for node kl
        const float* ap = ws + OFF_ADVP;
        int i = b * 32 + kl;
        float a = 0.f;
        #pragma unroll
        for (int j = 0; j < 4; ++j) a += ap[(size_t)(4 * g + j) * NN + i];
        amat[g * 33 + kl] = a;
    }
    __syncthreads();
    if (tid < 32) {
        float sv = 0.f, av = 0.f;
        #pragma unroll
        for (int j = 0; j < 32; ++j) {
            sv += gmat[j * 33 + tid];
            av += amat[j * 33 + tid];
        }
        int i = b * 32 + tid;
        ws[OFF_S + i]    = sv;
        ws[OFF_ADVF + i] = av;
        float part = sv * att[NN + i];       // s.a2 partial (k == i window)
        #pragma unroll
        for (int off = 16; off > 0; off >>= 1) part += __shfl_down(part, off);
        if (tid == 0) ws[OFF_S1P + b] = part;
    }
    __syncthreads();
    if (tid == 0) {
        unsigned old = bump(ws, OFF_CNT2);   // CNT2 zeroed by K1 this launch
        isLast = (old == NK4 - 1);
    }
    __syncthreads();
    if (!isLast) return;

    // ---- last block: scal1 -> alpha -> s2 -> out (fixed-order trees) ----
    smem[tid] = (tid < 256) ? ws[OFF_S1P + tid] : 0.f;
    __syncthreads();
    for (int off = 512; off > 0; off >>= 1) {
        if (tid < off) smem[tid] += smem[tid + off];
        __syncthreads();
    }
    const float scal1 = smem[0];
    const float c0 = ws[OFF_SC];
    __syncthreads();

    float advv[8], acc2 = 0.f;
    #pragma unroll
    for (int m = 0; m < 8; ++m) {
        int i = tid + m * 1024;
        float av = ws[OFF_ADVF + i];
        advv[m] = av;
        float a  = ws[OFF_XU + i] + c0 + av * scal1;
        float lr = a > 0.f ? a : 0.2f * a;
        acc2 += lr * ws[OFF_S + i];
    }
    smem[tid] = acc2;
    __syncthreads();
    for (int off = 512; off > 0; off >>= 1) {
        if (tid < off) smem[tid] += smem[tid + off];
        __syncthreads();
    }
    const float s2 = smem[0];
    #pragma unroll
    for (int m = 0; m < 8; ++m) {
        int i = tid + m * 1024;
        float v = advv[m] * s2 + bias[i];
        out[i] = v > 0.f ? v : 0.f;
    }
}

// ===========================================================================
extern "C" void kernel_launch(void* const* d_in, const int* in_sizes, int n_in,
                              void* d_out, int out_size, void* d_ws, size_t ws_size,
                              hipStream_t stream) {
    const float* x      = (const float*)d_in[0];   // [8192, 512]
    const int*   eidx   = (const int*)d_in[1];     // [2, E]
    const float* weight = (const float*)d_in[2];   // [512, 8192]
    const float* bias   = (const float*)d_in[3];   // [8192]
    const float* att    = (const float*)d_in[4];   // [16384]
    const float* lin_w  = (const float*)d_in[5];   // [8192, 512]
    const float* lin_b  = (const float*)d_in[6];   // [8192]

    const int E = in_sizes[1] / 2;
    const int* row = eidx;
    const int* col = eidx + E;
    float* ws  = (float*)d_ws;
    float* out = (float*)d_out;

    k1<<<NDEG + NU + 1, 1024, 0, stream>>>(lin_w, att, lin_b, row, E, ws);
    k2<<<NXB,      1024, 0, stream>>>(x, ws);
    k3<<<NADV + 1, 1024, 0, stream>>>(row, col, E, ws);
    k4<<<NK4,      1024, 0, stream>>>(weight, att, bias, ws, out);
}